// Round 5
// baseline (134.383 us; speedup 1.0000x reference)
//
#include <hip/hip_runtime.h>
#include <hip/hip_bf16.h>

// CrossModalContrastiveLoss: B=8, C=256, H=W=32 -> N=8192 vectors of dim 256.
// loss = -( P - 1024 * sum_i log(sum_j exp(S_ij)) ) / 8388608,
// S = normalize(rgb) @ normalize(x)^T / 0.1.
// positives for row i are cols j with j%8 == i/1024. A_q carries
// k2 = 10*log2(e) folded in at quantization, so S_mfma = k2*sim and
// exp(10*sim) = exp2(S_mfma).
//
// Round-14: R13 fixed the Pacc convoy (94->75us) but FETCH/WRITE jumped to
// 15.4/15.4 MB -- the signature of the remaining contended-RMW stream: 131k
// sumexp atomics at 256/cache-line (16 strips x 16 rows/line), now drained
// at the pre-done barrier (R10 never waited on them = its latent race).
// Fix: privatize per strip -- sumexp2d[strip][8192] (512 KB), every address
// written by exactly ONE block -> uncontended atomics, trivial drain.
// is_last folds the 16 strip-partials into the logf loop (512 coalesced
// loads/thread, one block, ~3us). norm zeroes the 512 KB (1 float/thread).

#define HWsz 1024
#define Cdim 256
#define Nvec 8192
#define CHW  (Cdim * HWsz)
#define NBLK 1024   // 16 strips x 64 rowgroups
#define NSTRIP 16

typedef __attribute__((ext_vector_type(4))) float f32x4;

// 32 vectors per block (all one batch), C split 8 ways. Quantizes to fp8
// e4m3 (rgb side pre-scaled by k2), stores (N,C) row-major. Also zeroes
// the accumulators the gemm kernel needs (replaces the memset dispatch).
__global__ __launch_bounds__(256) void norm_kernel(
    const float* __restrict__ rgb, const float* __restrict__ x,
    unsigned char* __restrict__ rgbq, unsigned char* __restrict__ xq,
    float* __restrict__ sumexp2d, float* __restrict__ Pblk,
    unsigned int* __restrict__ done) {
  __shared__ float ssp[8][32];
  __shared__ __align__(16) unsigned char tile[32][272];  // 272 = 16*17
  const int t = threadIdx.x;
  const int nl = t & 31;        // vector within block
  const int part = t >> 5;      // 0..7: channel chunk
  const int isx = blockIdx.y;
  const int bx = blockIdx.x;

  // ---- zero gemm accumulators (this kernel precedes gemm in-stream) ----
  // 512 blocks x 256 threads covers 16*8192 floats exactly.
  sumexp2d[(isx * 256 + bx) * 256 + t] = 0.f;
  if (t < 2)  Pblk[(isx * 256 + bx) * 2 + t] = 0.f;
  if (isx == 0 && bx == 0 && t == 63) *done = 0u;

  const float* src = isx ? x : rgb;
  unsigned char* dst = isx ? xq : rgbq;
  const int n0 = bx * 32;
  const int n = n0 + nl;
  const int b = n >> 10;        // uniform per block
  const int hw = n & 1023;
  const float* p = src + (size_t)b * CHW + (size_t)(part * 32) * HWsz + hw;

  float v[32];
  float ss = 0.f;
#pragma unroll
  for (int j = 0; j < 32; ++j) {
    v[j] = p[(size_t)j * HWsz];
    ss += v[j] * v[j];
  }
  ssp[part][nl] = ss;
  __syncthreads();
  float tot = 0.f;
#pragma unroll
  for (int q = 0; q < 8; ++q) tot += ssp[q][nl];
  const float k2 = 14.4269504089f;  // (1/T) * log2(e), folded into rgb side
  const float inv = (isx ? 1.0f : k2) / fmaxf(sqrtf(tot), 1e-12f);

#pragma unroll
  for (int c0 = 0; c0 < 32; c0 += 4) {
    int pk = 0;
    pk = __builtin_amdgcn_cvt_pk_fp8_f32(v[c0] * inv, v[c0 + 1] * inv, pk, false);
    pk = __builtin_amdgcn_cvt_pk_fp8_f32(v[c0 + 2] * inv, v[c0 + 3] * inv, pk, true);
    *reinterpret_cast<unsigned int*>(&tile[nl][part * 32 + c0]) =
        (unsigned int)pk;
  }
  __syncthreads();

  // coalesced store: 2 passes x (16 rows x 256 B)
#pragma unroll
  for (int pass = 0; pass < 2; ++pass) {
    const int r = pass * 16 + (t >> 4);
    const int ck = (t & 15) * 16;
    *reinterpret_cast<uint4*>(dst + (size_t)(n0 + r) * Cdim + ck) =
        *reinterpret_cast<const uint4*>(&tile[r][ck]);
  }
}

// Block = 4 waves, 128 rows x 512-col strip, fp8. A-panel 32 rows/wave in
// regs (8 s-steps x 2 mi longs = 32 VGPRs). B streamed as 8 chunks of 64
// cols x 256 K through double-buffered 2x16 KB LDS.
//
// fp8 LDS swizzle (16-B staging granule): col's 16 units placed at
//   phys(unit) = ((unit>>1) ^ (col&7) ^ ((unit&1)<<2)) + ((unit&1)<<3)
// Inverted on the GLOBAL address side so the wave-uniform base + lane*16
// constraint of global_load_lds is preserved.
__global__ __launch_bounds__(256, 4) void gemm_loss_kernel(
    const unsigned char* __restrict__ A, const unsigned char* __restrict__ Bq,
    float* __restrict__ sumexp2d, float* __restrict__ Pblk,
    unsigned int* __restrict__ done, float* __restrict__ out) {
  __shared__ __align__(16) unsigned char sB[2][16384];
  __shared__ float part4[4], part4b[4], pshare[4];
  __shared__ unsigned int is_last;

  const int tid  = threadIdx.x;
  const int lane = tid & 63;
  const int w    = tid >> 6;      // wave 0..3 -> rows w*32..+32
  const int strip = blockIdx.x;   // 0..15: cols strip*512..+512 (XCD-pinned)
  const int rg   = blockIdx.y;    // 0..63: rows rg*128..+128
  const int quad = lane >> 4;
  const int l15  = lane & 15;
  const int bi   = rg >> 3;       // batch of this rowgroup

  // ---- A fragments: direct global -> 32 regs/wave, once per block ----
  long areg[8][2];
#pragma unroll
  for (int mi = 0; mi < 2; ++mi) {
    const unsigned char* rp =
        A + (size_t)(rg * 128 + w * 32 + mi * 16 + l15) * Cdim + quad * 8;
#pragma unroll
    for (int s = 0; s < 8; ++s)
      areg[s][mi] = *reinterpret_cast<const long*>(rp + s * 32);
  }

  // staging lane constants: lane = c4*16 + u writes (col base+c4, slot u)
  const int u_  = l15;
  const int c4  = quad;
  const int gx  = (u_ & 7) ^ ((u_ >> 3) << 2);
  const int godd = u_ >> 3;   // global unit parity this slot holds
  // reader lane constants
  const int sxor = (l15 & 7) ^ ((quad >> 1) << 2);
  const int boff = ((quad >> 1) << 7) + ((quad & 1) << 3);

  float rowexp[8];
#pragma unroll
  for (int i = 0; i < 8; ++i) rowexp[i] = 0.f;
  float pp[4];   // 4 independent partial sums of raw acc (masked at end)
#pragma unroll
  for (int i = 0; i < 4; ++i) pp[i] = 0.f;

  const unsigned char* Bbase = Bq + (size_t)strip * 512 * Cdim;

  // prefetch chunk 0
#pragma unroll
  for (int i = 0; i < 4; ++i) {
    const int colw = w * 16 + i * 4 + c4;
    const unsigned char* gp = Bbase + (size_t)colw * Cdim +
                              32 * (gx ^ (colw & 7)) + godd * 16;
    unsigned char* lp = &sB[0][(w * 16 + i * 4) * 256];
    __builtin_amdgcn_global_load_lds(
        (const __attribute__((address_space(1))) void*)gp,
        (__attribute__((address_space(3))) void*)lp, 16, 0, 0);
  }
  __syncthreads();

  for (int c = 0; c < 8; ++c) {
    const int bf = c & 1;
    if (c < 7) {  // prefetch next chunk (overlaps this chunk's MFMA)
#pragma unroll
      for (int i = 0; i < 4; ++i) {
        const int colw = w * 16 + i * 4 + c4;
        const unsigned char* gp = Bbase + (size_t)((c + 1) * 64 + colw) * Cdim +
                                  32 * (gx ^ (colw & 7)) + godd * 16;
        unsigned char* lp = &sB[bf ^ 1][(w * 16 + i * 4) * 256];
        __builtin_amdgcn_global_load_lds(
            (const __attribute__((address_space(1))) void*)gp,
            (__attribute__((address_space(3))) void*)lp, 16, 0, 0);
      }
    }

    // Two 32-col slices per chunk; slice p's exp2 phase overlaps slice
    // p+1's reads/MFMAs.
    for (int p = 0; p < 2; ++p) {
      long bfr[2][8];
#pragma unroll
      for (int j = 0; j < 2; ++j)
#pragma unroll
        for (int s = 0; s < 8; ++s)
          bfr[j][s] = *reinterpret_cast<const long*>(
              &sB[bf][((p * 2 + j) * 16 + l15) * 256 +
                      (((s ^ sxor) << 4) + boff)]);

      f32x4 acc[2][2];
#pragma unroll
      for (int mi = 0; mi < 2; ++mi)
#pragma unroll
        for (int j = 0; j < 2; ++j) acc[mi][j] = (f32x4){0.f, 0.f, 0.f, 0.f};

      __builtin_amdgcn_s_setprio(1);
#pragma unroll
      for (int s = 0; s < 8; ++s)
#pragma unroll
        for (int mi = 0; mi < 2; ++mi)
#pragma unroll
          for (int j = 0; j < 2; ++j)
            acc[mi][j] = __builtin_amdgcn_mfma_f32_16x16x32_fp8_fp8(
                areg[s][mi], bfr[j][s], acc[mi][j], 0, 0, 0);
      __builtin_amdgcn_s_setprio(0);

      // rowexp += exp2(S_mfma)  (k2 pre-folded into A); pp[] collects the
      // raw acc sum for the analytic positive term (4 independent chains).
#pragma unroll
      for (int mi = 0; mi < 2; ++mi)
#pragma unroll
        for (int j = 0; j < 2; ++j)
#pragma unroll
          for (int r = 0; r < 4; ++r) {
            rowexp[mi * 4 + r] += __builtin_amdgcn_exp2f(acc[mi][j][r]);
            pp[r] += acc[mi][j][r];
          }
    }

    __syncthreads();  // buffer reuse; prefetch had full compute to land
  }

  // ---- epilogue: one reduce + uncontended atomic per row slot into this
  // strip's private slice (each address written by exactly one block) ----
#pragma unroll
  for (int idx = 0; idx < 8; ++idx) {
    float se = rowexp[idx];
    se += __shfl_xor(se, 1);
    se += __shfl_xor(se, 2);
    se += __shfl_xor(se, 4);
    se += __shfl_xor(se, 8);
    if (l15 == 0) {
      const int row =
          rg * 128 + w * 32 + (idx >> 2) * 16 + quad * 4 + (idx & 3);
      atomicAdd(&sumexp2d[strip * Nvec + row], se);
    }
  }

  // ---- positive-pair term: lane's cols are ≡ l15 (mod 8); per-block
  // LDS reduce -> ONE atomic to a block-private address (no contention) ----
  float pl = ((l15 & 7) == bi) ? (pp[0] + pp[1]) + (pp[2] + pp[3]) : 0.f;
#pragma unroll
  for (int off = 1; off < 64; off <<= 1) pl += __shfl_xor(pl, off);
  if (lane == 0) pshare[w] = pl;

  // barrier: publishes pshare AND drains all waves' atomics (visibility);
  // drain is cheap now -- every atomic targets a block-private address.
  __syncthreads();
  if (tid == 0) {
    atomicAdd(&Pblk[rg * 16 + strip],
              (pshare[0] + pshare[1]) + (pshare[2] + pshare[3]));
    __threadfence();
    is_last = (atomicAdd(done, 1u) == NBLK - 1) ? 1u : 0u;
  }
  __syncthreads();

  // ---- last block finalizes the loss ----
  if (is_last) {
    __threadfence();  // acquire: all blocks' atomics visible
    float lsum = 0.f, pb = 0.f;
    for (int i = tid; i < Nvec; i += 256) {
      float rs = 0.f;
#pragma unroll
      for (int s = 0; s < NSTRIP; ++s) rs += sumexp2d[s * Nvec + i];
      lsum += logf(rs);
    }
#pragma unroll
    for (int i = 0; i < NBLK / 256; ++i) pb += Pblk[i * 256 + tid];
#pragma unroll
    for (int off = 1; off < 64; off <<= 1) {
      lsum += __shfl_xor(lsum, off);
      pb   += __shfl_xor(pb, off);
    }
    if ((tid & 63) == 0) { part4[w] = lsum; part4b[w] = pb; }
    __syncthreads();
    if (tid == 0) {
      float total_lse = 0.f, P = 0.f;
#pragma unroll
      for (int i = 0; i < 4; ++i) { total_lse += part4[i]; P += part4b[i]; }
      // acc = k2*sim, ln2*k2 = 1/T -> P*ln2 = sum_pos sim/T
      P *= 0.69314718056f;  // ln 2
      out[0] = -(P - 1024.0f * total_lse) / (8388608.0f + 1e-8f);
    }
  }
}

extern "C" void kernel_launch(void* const* d_in, const int* in_sizes, int n_in,
                              void* d_out, int out_size, void* d_ws,
                              size_t ws_size, hipStream_t stream) {
  const float* rgb = (const float*)d_in[0];
  const float* x   = (const float*)d_in[1];
  char* ws = (char*)d_ws;
  unsigned char* rgbq = (unsigned char*)ws;                             // 2 MiB
  unsigned char* xq   = (unsigned char*)(ws + (size_t)2 * 1024 * 1024); // 2 MiB
  float* sumexp2d = (float*)(ws + (size_t)4 * 1024 * 1024);  // 16x8192 floats
  float* Pblk     = sumexp2d + NSTRIP * Nvec;                // 1024 floats
  unsigned int* done = (unsigned int*)(Pblk + NBLK);

  // no memset dispatch: norm_kernel zeroes sumexp2d/Pblk/done
  norm_kernel<<<dim3(256, 2), 256, 0, stream>>>(rgb, x, rgbq, xq, sumexp2d,
                                                Pblk, done);
  gemm_loss_kernel<<<dim3(16, 64), 256, 0, stream>>>(rgbq, xq, sumexp2d, Pblk,
                                                     done, (float*)d_out);
}

// Round 6
// 131.176 us; speedup vs baseline: 1.0245x; 1.0245x over previous
//
#include <hip/hip_runtime.h>
#include <hip/hip_bf16.h>

// CrossModalContrastiveLoss: B=8, C=256, H=W=32 -> N=8192 vectors of dim 256.
// loss = -( P - 1024 * sum_i log(sum_j exp(S_ij)) ) / 8388608,
// S = normalize(rgb) @ normalize(x)^T / 0.1.
// positives for row i are cols j with j%8 == i/1024. A_q carries
// k2 = 10*log2(e) folded in at quantization, so S_mfma = k2*sim and
// exp(10*sim) = exp2(S_mfma).
//
// Round-15: WRITE_SIZE was byte-identical (15424 KB) across R13/R14 despite
// a 16x footprint and contention change in the sumexp accumulator ->
// the 15 KB/block write stream is SCRATCH SPILL, not atomics. Live regs
// (areg 32 + bfr 32 + acc 16 + rowexp 8 + pp 4 + addr) ~ 100 > the 64 the
// compiler allocated (it targets 8 waves/EU, unreachable: LDS caps us at 4
// blocks/CU = 4 waves/EU). MFMA busy time is ~12.7us in every round; all
// regression was spill stall. Fix: amdgpu_waves_per_eu(4,4) pins the real
// occupancy and unlocks the 128-VGPR budget. Body identical to R13
// (shared sumexp[8192], per-block Pblk, pp[4]); the attribute is the only
// experiment.

#define HWsz 1024
#define Cdim 256
#define Nvec 8192
#define CHW  (Cdim * HWsz)
#define NBLK 1024   // 16 strips x 64 rowgroups

typedef __attribute__((ext_vector_type(4))) float f32x4;

// 32 vectors per block (all one batch), C split 8 ways. Quantizes to fp8
// e4m3 (rgb side pre-scaled by k2), stores (N,C) row-major. Also zeroes
// the accumulators the gemm kernel needs (replaces the memset dispatch).
__global__ __launch_bounds__(256) void norm_kernel(
    const float* __restrict__ rgb, const float* __restrict__ x,
    unsigned char* __restrict__ rgbq, unsigned char* __restrict__ xq,
    float* __restrict__ sumexp, float* __restrict__ Pblk,
    unsigned int* __restrict__ done) {
  __shared__ float ssp[8][32];
  __shared__ __align__(16) unsigned char tile[32][272];  // 272 = 16*17
  const int t = threadIdx.x;
  const int nl = t & 31;        // vector within block
  const int part = t >> 5;      // 0..7: channel chunk
  const int isx = blockIdx.y;
  const int bx = blockIdx.x;

  // ---- zero gemm accumulators (this kernel precedes gemm in-stream) ----
  if (t < 16) sumexp[(isx * 256 + bx) * 16 + t] = 0.f;
  if (t < 2)  Pblk[(isx * 256 + bx) * 2 + t] = 0.f;
  if (isx == 0 && bx == 0 && t == 63) *done = 0u;

  const float* src = isx ? x : rgb;
  unsigned char* dst = isx ? xq : rgbq;
  const int n0 = bx * 32;
  const int n = n0 + nl;
  const int b = n >> 10;        // uniform per block
  const int hw = n & 1023;
  const float* p = src + (size_t)b * CHW + (size_t)(part * 32) * HWsz + hw;

  float v[32];
  float ss = 0.f;
#pragma unroll
  for (int j = 0; j < 32; ++j) {
    v[j] = p[(size_t)j * HWsz];
    ss += v[j] * v[j];
  }
  ssp[part][nl] = ss;
  __syncthreads();
  float tot = 0.f;
#pragma unroll
  for (int q = 0; q < 8; ++q) tot += ssp[q][nl];
  const float k2 = 14.4269504089f;  // (1/T) * log2(e), folded into rgb side
  const float inv = (isx ? 1.0f : k2) / fmaxf(sqrtf(tot), 1e-12f);

#pragma unroll
  for (int c0 = 0; c0 < 32; c0 += 4) {
    int pk = 0;
    pk = __builtin_amdgcn_cvt_pk_fp8_f32(v[c0] * inv, v[c0 + 1] * inv, pk, false);
    pk = __builtin_amdgcn_cvt_pk_fp8_f32(v[c0 + 2] * inv, v[c0 + 3] * inv, pk, true);
    *reinterpret_cast<unsigned int*>(&tile[nl][part * 32 + c0]) =
        (unsigned int)pk;
  }
  __syncthreads();

  // coalesced store: 2 passes x (16 rows x 256 B)
#pragma unroll
  for (int pass = 0; pass < 2; ++pass) {
    const int r = pass * 16 + (t >> 4);
    const int ck = (t & 15) * 16;
    *reinterpret_cast<uint4*>(dst + (size_t)(n0 + r) * Cdim + ck) =
        *reinterpret_cast<const uint4*>(&tile[r][ck]);
  }
}

// Block = 4 waves, 128 rows x 512-col strip, fp8. A-panel 32 rows/wave in
// regs (8 s-steps x 2 mi longs = 32 VGPRs). B streamed as 8 chunks of 64
// cols x 256 K through double-buffered 2x16 KB LDS.
//
// fp8 LDS swizzle (16-B staging granule): col's 16 units placed at
//   phys(unit) = ((unit>>1) ^ (col&7) ^ ((unit&1)<<2)) + ((unit&1)<<3)
// Inverted on the GLOBAL address side so the wave-uniform base + lane*16
// constraint of global_load_lds is preserved.
//
// amdgpu_waves_per_eu(4,4): LDS (33 KB/block) caps residency at 4 blocks/CU
// = 4 waves/EU; pinning it tells the allocator the full 128-VGPR budget is
// free, eliminating the hot-loop spill that 64-VGPR allocation caused.
__global__ __launch_bounds__(256)
__attribute__((amdgpu_waves_per_eu(4, 4))) void gemm_loss_kernel(
    const unsigned char* __restrict__ A, const unsigned char* __restrict__ Bq,
    float* __restrict__ sumexp, float* __restrict__ Pblk,
    unsigned int* __restrict__ done, float* __restrict__ out) {
  __shared__ __align__(16) unsigned char sB[2][16384];
  __shared__ float part4[4], part4b[4], pshare[4];
  __shared__ unsigned int is_last;

  const int tid  = threadIdx.x;
  const int lane = tid & 63;
  const int w    = tid >> 6;      // wave 0..3 -> rows w*32..+32
  const int strip = blockIdx.x;   // 0..15: cols strip*512..+512 (XCD-pinned)
  const int rg   = blockIdx.y;    // 0..63: rows rg*128..+128
  const int quad = lane >> 4;
  const int l15  = lane & 15;
  const int bi   = rg >> 3;       // batch of this rowgroup

  // ---- A fragments: direct global -> 32 regs/wave, once per block ----
  long areg[8][2];
#pragma unroll
  for (int mi = 0; mi < 2; ++mi) {
    const unsigned char* rp =
        A + (size_t)(rg * 128 + w * 32 + mi * 16 + l15) * Cdim + quad * 8;
#pragma unroll
    for (int s = 0; s < 8; ++s)
      areg[s][mi] = *reinterpret_cast<const long*>(rp + s * 32);
  }

  // staging lane constants: lane = c4*16 + u writes (col base+c4, slot u)
  const int u_  = l15;
  const int c4  = quad;
  const int gx  = (u_ & 7) ^ ((u_ >> 3) << 2);
  const int godd = u_ >> 3;   // global unit parity this slot holds
  // reader lane constants
  const int sxor = (l15 & 7) ^ ((quad >> 1) << 2);
  const int boff = ((quad >> 1) << 7) + ((quad & 1) << 3);

  float rowexp[8];
#pragma unroll
  for (int i = 0; i < 8; ++i) rowexp[i] = 0.f;
  float pp[4];   // 4 independent partial sums of raw acc (masked at end)
#pragma unroll
  for (int i = 0; i < 4; ++i) pp[i] = 0.f;

  const unsigned char* Bbase = Bq + (size_t)strip * 512 * Cdim;

  // prefetch chunk 0
#pragma unroll
  for (int i = 0; i < 4; ++i) {
    const int colw = w * 16 + i * 4 + c4;
    const unsigned char* gp = Bbase + (size_t)colw * Cdim +
                              32 * (gx ^ (colw & 7)) + godd * 16;
    unsigned char* lp = &sB[0][(w * 16 + i * 4) * 256];
    __builtin_amdgcn_global_load_lds(
        (const __attribute__((address_space(1))) void*)gp,
        (__attribute__((address_space(3))) void*)lp, 16, 0, 0);
  }
  __syncthreads();

  for (int c = 0; c < 8; ++c) {
    const int bf = c & 1;
    if (c < 7) {  // prefetch next chunk (overlaps this chunk's MFMA)
#pragma unroll
      for (int i = 0; i < 4; ++i) {
        const int colw = w * 16 + i * 4 + c4;
        const unsigned char* gp = Bbase + (size_t)((c + 1) * 64 + colw) * Cdim +
                                  32 * (gx ^ (colw & 7)) + godd * 16;
        unsigned char* lp = &sB[bf ^ 1][(w * 16 + i * 4) * 256];
        __builtin_amdgcn_global_load_lds(
            (const __attribute__((address_space(1))) void*)gp,
            (__attribute__((address_space(3))) void*)lp, 16, 0, 0);
      }
    }

    // Two 32-col slices per chunk; slice p's exp2 phase overlaps slice
    // p+1's reads/MFMAs.
    for (int p = 0; p < 2; ++p) {
      long bfr[2][8];
#pragma unroll
      for (int j = 0; j < 2; ++j)
#pragma unroll
        for (int s = 0; s < 8; ++s)
          bfr[j][s] = *reinterpret_cast<const long*>(
              &sB[bf][((p * 2 + j) * 16 + l15) * 256 +
                      (((s ^ sxor) << 4) + boff)]);

      f32x4 acc[2][2];
#pragma unroll
      for (int mi = 0; mi < 2; ++mi)
#pragma unroll
        for (int j = 0; j < 2; ++j) acc[mi][j] = (f32x4){0.f, 0.f, 0.f, 0.f};

      __builtin_amdgcn_s_setprio(1);
#pragma unroll
      for (int s = 0; s < 8; ++s)
#pragma unroll
        for (int mi = 0; mi < 2; ++mi)
#pragma unroll
          for (int j = 0; j < 2; ++j)
            acc[mi][j] = __builtin_amdgcn_mfma_f32_16x16x32_fp8_fp8(
                areg[s][mi], bfr[j][s], acc[mi][j], 0, 0, 0);
      __builtin_amdgcn_s_setprio(0);

      // rowexp += exp2(S_mfma)  (k2 pre-folded into A); pp[] collects the
      // raw acc sum for the analytic positive term (4 independent chains).
#pragma unroll
      for (int mi = 0; mi < 2; ++mi)
#pragma unroll
        for (int j = 0; j < 2; ++j)
#pragma unroll
          for (int r = 0; r < 4; ++r) {
            rowexp[mi * 4 + r] += __builtin_amdgcn_exp2f(acc[mi][j][r]);
            pp[r] += acc[mi][j][r];
          }
    }

    __syncthreads();  // buffer reuse; prefetch had full compute to land
  }

  // ---- epilogue: one reduce + atomic per row slot ----
#pragma unroll
  for (int idx = 0; idx < 8; ++idx) {
    float se = rowexp[idx];
    se += __shfl_xor(se, 1);
    se += __shfl_xor(se, 2);
    se += __shfl_xor(se, 4);
    se += __shfl_xor(se, 8);
    if (l15 == 0) {
      const int row =
          rg * 128 + w * 32 + (idx >> 2) * 16 + quad * 4 + (idx & 3);
      atomicAdd(&sumexp[row], se);
    }
  }

  // ---- positive-pair term: lane's cols are ≡ l15 (mod 8); per-block
  // LDS reduce -> ONE atomic to a block-private address (no contention) ----
  float pl = ((l15 & 7) == bi) ? (pp[0] + pp[1]) + (pp[2] + pp[3]) : 0.f;
#pragma unroll
  for (int off = 1; off < 64; off <<= 1) pl += __shfl_xor(pl, off);
  if (lane == 0) pshare[w] = pl;

  // barrier: publishes pshare AND drains all waves' atomics (visibility).
  __syncthreads();
  if (tid == 0) {
    atomicAdd(&Pblk[rg * 16 + strip],
              (pshare[0] + pshare[1]) + (pshare[2] + pshare[3]));
    __threadfence();
    is_last = (atomicAdd(done, 1u) == NBLK - 1) ? 1u : 0u;
  }
  __syncthreads();

  // ---- last block finalizes the loss ----
  if (is_last) {
    __threadfence();  // acquire: all blocks' atomics visible
    float lsum = 0.f, pb = 0.f;
    for (int i = tid; i < Nvec; i += 256) lsum += logf(sumexp[i]);
#pragma unroll
    for (int i = 0; i < NBLK / 256; ++i) pb += Pblk[i * 256 + tid];
#pragma unroll
    for (int off = 1; off < 64; off <<= 1) {
      lsum += __shfl_xor(lsum, off);
      pb   += __shfl_xor(pb, off);
    }
    if ((tid & 63) == 0) { part4[w] = lsum; part4b[w] = pb; }
    __syncthreads();
    if (tid == 0) {
      float total_lse = 0.f, P = 0.f;
#pragma unroll
      for (int i = 0; i < 4; ++i) { total_lse += part4[i]; P += part4b[i]; }
      // acc = k2*sim, ln2*k2 = 1/T -> P*ln2 = sum_pos sim/T
      P *= 0.69314718056f;  // ln 2
      out[0] = -(P - 1024.0f * total_lse) / (8388608.0f + 1e-8f);
    }
  }
}

extern "C" void kernel_launch(void* const* d_in, const int* in_sizes, int n_in,
                              void* d_out, int out_size, void* d_ws,
                              size_t ws_size, hipStream_t stream) {
  const float* rgb = (const float*)d_in[0];
  const float* x   = (const float*)d_in[1];
  char* ws = (char*)d_ws;
  unsigned char* rgbq = (unsigned char*)ws;                             // 2 MiB
  unsigned char* xq   = (unsigned char*)(ws + (size_t)2 * 1024 * 1024); // 2 MiB
  float* sumexp = (float*)(ws + (size_t)4 * 1024 * 1024);  // 8192 floats
  float* Pblk   = sumexp + Nvec;                           // 1024 floats
  unsigned int* done = (unsigned int*)(Pblk + NBLK);

  // no memset dispatch: norm_kernel zeroes sumexp/Pblk/done
  norm_kernel<<<dim3(256, 2), 256, 0, stream>>>(rgb, x, rgbq, xq, sumexp,
                                                Pblk, done);
  gemm_loss_kernel<<<dim3(16, 64), 256, 0, stream>>>(rgbq, xq, sumexp, Pblk,
                                                     done, (float*)d_out);
}

// Round 7
// 118.313 us; speedup vs baseline: 1.1358x; 1.1087x over previous
//
#include <hip/hip_runtime.h>
#include <hip/hip_bf16.h>

// CrossModalContrastiveLoss: B=8, C=256, H=W=32 -> N=8192 vectors of dim 256.
// loss = -( P - 1024 * sum_i log(sum_j exp(S_ij)) ) / 8388608,
// S = normalize(rgb) @ normalize(x)^T / 0.1.
// positives for row i are cols j with j%8 == i/1024. A_q carries
// k2 = 10*log2(e) folded in at quantization, so S_mfma = k2*sim and
// exp(10*sim) = exp2(S_mfma).
//
// Round-16: the ~13 MB write stream (byte-identical across R13/R14/R15) is
// a fixed ~13 KB/block scratch footprint -> spill. The allocator pins 64
// arch-VGPRs regardless of launch_bounds/waves_per_eu (both ignored), and
// the R12->R13 change (pAll -> pp[4], +3 live regs in the hot loop) pushed
// the loop over the 64-reg cliff (R12: WRITE 2.2 MB; R13+: 15.4 MB). Fix
// at the source: revert the loop to R12's exact register set (single pAll
// accumulator), KEEP R13's per-block Pblk epilogue (the Pacc-convoy fix,
// epilogue-only). Attributes dropped -- they did nothing.

#define HWsz 1024
#define Cdim 256
#define Nvec 8192
#define CHW  (Cdim * HWsz)
#define NBLK 1024   // 16 strips x 64 rowgroups

typedef __attribute__((ext_vector_type(4))) float f32x4;

// 32 vectors per block (all one batch), C split 8 ways. Quantizes to fp8
// e4m3 (rgb side pre-scaled by k2), stores (N,C) row-major. Also zeroes
// the accumulators the gemm kernel needs (replaces the memset dispatch).
__global__ __launch_bounds__(256) void norm_kernel(
    const float* __restrict__ rgb, const float* __restrict__ x,
    unsigned char* __restrict__ rgbq, unsigned char* __restrict__ xq,
    float* __restrict__ sumexp, float* __restrict__ Pblk,
    unsigned int* __restrict__ done) {
  __shared__ float ssp[8][32];
  __shared__ __align__(16) unsigned char tile[32][272];  // 272 = 16*17
  const int t = threadIdx.x;
  const int nl = t & 31;        // vector within block
  const int part = t >> 5;      // 0..7: channel chunk
  const int isx = blockIdx.y;
  const int bx = blockIdx.x;

  // ---- zero gemm accumulators (this kernel precedes gemm in-stream) ----
  if (t < 16) sumexp[(isx * 256 + bx) * 16 + t] = 0.f;
  if (t < 2)  Pblk[(isx * 256 + bx) * 2 + t] = 0.f;
  if (isx == 0 && bx == 0 && t == 63) *done = 0u;

  const float* src = isx ? x : rgb;
  unsigned char* dst = isx ? xq : rgbq;
  const int n0 = bx * 32;
  const int n = n0 + nl;
  const int b = n >> 10;        // uniform per block
  const int hw = n & 1023;
  const float* p = src + (size_t)b * CHW + (size_t)(part * 32) * HWsz + hw;

  float v[32];
  float ss = 0.f;
#pragma unroll
  for (int j = 0; j < 32; ++j) {
    v[j] = p[(size_t)j * HWsz];
    ss += v[j] * v[j];
  }
  ssp[part][nl] = ss;
  __syncthreads();
  float tot = 0.f;
#pragma unroll
  for (int q = 0; q < 8; ++q) tot += ssp[q][nl];
  const float k2 = 14.4269504089f;  // (1/T) * log2(e), folded into rgb side
  const float inv = (isx ? 1.0f : k2) / fmaxf(sqrtf(tot), 1e-12f);

#pragma unroll
  for (int c0 = 0; c0 < 32; c0 += 4) {
    int pk = 0;
    pk = __builtin_amdgcn_cvt_pk_fp8_f32(v[c0] * inv, v[c0 + 1] * inv, pk, false);
    pk = __builtin_amdgcn_cvt_pk_fp8_f32(v[c0 + 2] * inv, v[c0 + 3] * inv, pk, true);
    *reinterpret_cast<unsigned int*>(&tile[nl][part * 32 + c0]) =
        (unsigned int)pk;
  }
  __syncthreads();

  // coalesced store: 2 passes x (16 rows x 256 B)
#pragma unroll
  for (int pass = 0; pass < 2; ++pass) {
    const int r = pass * 16 + (t >> 4);
    const int ck = (t & 15) * 16;
    *reinterpret_cast<uint4*>(dst + (size_t)(n0 + r) * Cdim + ck) =
        *reinterpret_cast<const uint4*>(&tile[r][ck]);
  }
}

// Block = 4 waves, 128 rows x 512-col strip, fp8. A-panel 32 rows/wave in
// regs (8 s-steps x 2 mi longs = 32 VGPRs). B streamed as 8 chunks of 64
// cols x 256 K through double-buffered 2x16 KB LDS.
//
// fp8 LDS swizzle (16-B staging granule): col's 16 units placed at
//   phys(unit) = ((unit>>1) ^ (col&7) ^ ((unit&1)<<2)) + ((unit&1)<<3)
// Inverted on the GLOBAL address side so the wave-uniform base + lane*16
// constraint of global_load_lds is preserved.
__global__ __launch_bounds__(256, 4) void gemm_loss_kernel(
    const unsigned char* __restrict__ A, const unsigned char* __restrict__ Bq,
    float* __restrict__ sumexp, float* __restrict__ Pblk,
    unsigned int* __restrict__ done, float* __restrict__ out) {
  __shared__ __align__(16) unsigned char sB[2][16384];
  __shared__ float part4[4], part4b[4], pshare[4];
  __shared__ unsigned int is_last;

  const int tid  = threadIdx.x;
  const int lane = tid & 63;
  const int w    = tid >> 6;      // wave 0..3 -> rows w*32..+32
  const int strip = blockIdx.x;   // 0..15: cols strip*512..+512 (XCD-pinned)
  const int rg   = blockIdx.y;    // 0..63: rows rg*128..+128
  const int quad = lane >> 4;
  const int l15  = lane & 15;
  const int bi   = rg >> 3;       // batch of this rowgroup

  // ---- A fragments: direct global -> 32 regs/wave, once per block ----
  long areg[8][2];
#pragma unroll
  for (int mi = 0; mi < 2; ++mi) {
    const unsigned char* rp =
        A + (size_t)(rg * 128 + w * 32 + mi * 16 + l15) * Cdim + quad * 8;
#pragma unroll
    for (int s = 0; s < 8; ++s)
      areg[s][mi] = *reinterpret_cast<const long*>(rp + s * 32);
  }

  // staging lane constants: lane = c4*16 + u writes (col base+c4, slot u)
  const int u_  = l15;
  const int c4  = quad;
  const int gx  = (u_ & 7) ^ ((u_ >> 3) << 2);
  const int godd = u_ >> 3;   // global unit parity this slot holds
  // reader lane constants
  const int sxor = (l15 & 7) ^ ((quad >> 1) << 2);
  const int boff = ((quad >> 1) << 7) + ((quad & 1) << 3);

  float rowexp[8];
#pragma unroll
  for (int i = 0; i < 8; ++i) rowexp[i] = 0.f;
  float pAll = 0.f;   // single accumulator: R12's exact loop register set

  const unsigned char* Bbase = Bq + (size_t)strip * 512 * Cdim;

  // prefetch chunk 0
#pragma unroll
  for (int i = 0; i < 4; ++i) {
    const int colw = w * 16 + i * 4 + c4;
    const unsigned char* gp = Bbase + (size_t)colw * Cdim +
                              32 * (gx ^ (colw & 7)) + godd * 16;
    unsigned char* lp = &sB[0][(w * 16 + i * 4) * 256];
    __builtin_amdgcn_global_load_lds(
        (const __attribute__((address_space(1))) void*)gp,
        (__attribute__((address_space(3))) void*)lp, 16, 0, 0);
  }
  __syncthreads();

  for (int c = 0; c < 8; ++c) {
    const int bf = c & 1;
    if (c < 7) {  // prefetch next chunk (overlaps this chunk's MFMA)
#pragma unroll
      for (int i = 0; i < 4; ++i) {
        const int colw = w * 16 + i * 4 + c4;
        const unsigned char* gp = Bbase + (size_t)((c + 1) * 64 + colw) * Cdim +
                                  32 * (gx ^ (colw & 7)) + godd * 16;
        unsigned char* lp = &sB[bf ^ 1][(w * 16 + i * 4) * 256];
        __builtin_amdgcn_global_load_lds(
            (const __attribute__((address_space(1))) void*)gp,
            (__attribute__((address_space(3))) void*)lp, 16, 0, 0);
      }
    }

    // Two 32-col slices per chunk; slice p's exp2 phase overlaps slice
    // p+1's reads/MFMAs.
    for (int p = 0; p < 2; ++p) {
      long bfr[2][8];
#pragma unroll
      for (int j = 0; j < 2; ++j)
#pragma unroll
        for (int s = 0; s < 8; ++s)
          bfr[j][s] = *reinterpret_cast<const long*>(
              &sB[bf][((p * 2 + j) * 16 + l15) * 256 +
                      (((s ^ sxor) << 4) + boff)]);

      f32x4 acc[2][2];
#pragma unroll
      for (int mi = 0; mi < 2; ++mi)
#pragma unroll
        for (int j = 0; j < 2; ++j) acc[mi][j] = (f32x4){0.f, 0.f, 0.f, 0.f};

      __builtin_amdgcn_s_setprio(1);
#pragma unroll
      for (int s = 0; s < 8; ++s)
#pragma unroll
        for (int mi = 0; mi < 2; ++mi)
#pragma unroll
          for (int j = 0; j < 2; ++j)
            acc[mi][j] = __builtin_amdgcn_mfma_f32_16x16x32_fp8_fp8(
                areg[s][mi], bfr[j][s], acc[mi][j], 0, 0, 0);
      __builtin_amdgcn_s_setprio(0);

      // rowexp += exp2(S_mfma)  (k2 pre-folded into A); pAll collects the
      // raw acc sum for the analytic positive term.
#pragma unroll
      for (int mi = 0; mi < 2; ++mi)
#pragma unroll
        for (int j = 0; j < 2; ++j)
#pragma unroll
          for (int r = 0; r < 4; ++r) {
            rowexp[mi * 4 + r] += __builtin_amdgcn_exp2f(acc[mi][j][r]);
            pAll += acc[mi][j][r];
          }
    }

    __syncthreads();  // buffer reuse; prefetch had full compute to land
  }

  // ---- epilogue: one reduce + atomic per row slot ----
#pragma unroll
  for (int idx = 0; idx < 8; ++idx) {
    float se = rowexp[idx];
    se += __shfl_xor(se, 1);
    se += __shfl_xor(se, 2);
    se += __shfl_xor(se, 4);
    se += __shfl_xor(se, 8);
    if (l15 == 0) {
      const int row =
          rg * 128 + w * 32 + (idx >> 2) * 16 + quad * 4 + (idx & 3);
      atomicAdd(&sumexp[row], se);
    }
  }

  // ---- positive-pair term: lane's cols are ≡ l15 (mod 8); per-block
  // LDS reduce -> ONE atomic to a block-private address (no contention) ----
  float pl = ((l15 & 7) == bi) ? pAll : 0.f;
#pragma unroll
  for (int off = 1; off < 64; off <<= 1) pl += __shfl_xor(pl, off);
  if (lane == 0) pshare[w] = pl;

  // barrier: publishes pshare AND drains all waves' atomics (visibility);
  // drain is cheap -- every atomic targets low-contention addresses.
  __syncthreads();
  if (tid == 0) {
    atomicAdd(&Pblk[rg * 16 + strip],
              (pshare[0] + pshare[1]) + (pshare[2] + pshare[3]));
    __threadfence();
    is_last = (atomicAdd(done, 1u) == NBLK - 1) ? 1u : 0u;
  }
  __syncthreads();

  // ---- last block finalizes the loss ----
  if (is_last) {
    __threadfence();  // acquire: all blocks' atomics visible
    float lsum = 0.f, pb = 0.f;
    for (int i = tid; i < Nvec; i += 256) lsum += logf(sumexp[i]);
#pragma unroll
    for (int i = 0; i < NBLK / 256; ++i) pb += Pblk[i * 256 + tid];
#pragma unroll
    for (int off = 1; off < 64; off <<= 1) {
      lsum += __shfl_xor(lsum, off);
      pb   += __shfl_xor(pb, off);
    }
    if ((tid & 63) == 0) { part4[w] = lsum; part4b[w] = pb; }
    __syncthreads();
    if (tid == 0) {
      float total_lse = 0.f, P = 0.f;
#pragma unroll
      for (int i = 0; i < 4; ++i) { total_lse += part4[i]; P += part4b[i]; }
      // acc = k2*sim, ln2*k2 = 1/T -> P*ln2 = sum_pos sim/T
      P *= 0.69314718056f;  // ln 2
      out[0] = -(P - 1024.0f * total_lse) / (8388608.0f + 1e-8f);
    }
  }
}

extern "C" void kernel_launch(void* const* d_in, const int* in_sizes, int n_in,
                              void* d_out, int out_size, void* d_ws,
                              size_t ws_size, hipStream_t stream) {
  const float* rgb = (const float*)d_in[0];
  const float* x   = (const float*)d_in[1];
  char* ws = (char*)d_ws;
  unsigned char* rgbq = (unsigned char*)ws;                             // 2 MiB
  unsigned char* xq   = (unsigned char*)(ws + (size_t)2 * 1024 * 1024); // 2 MiB
  float* sumexp = (float*)(ws + (size_t)4 * 1024 * 1024);  // 8192 floats
  float* Pblk   = sumexp + Nvec;                           // 1024 floats
  unsigned int* done = (unsigned int*)(Pblk + NBLK);

  // no memset dispatch: norm_kernel zeroes sumexp/Pblk/done
  norm_kernel<<<dim3(256, 2), 256, 0, stream>>>(rgb, x, rgbq, xq, sumexp,
                                                Pblk, done);
  gemm_loss_kernel<<<dim3(16, 64), 256, 0, stream>>>(rgbq, xq, sumexp, Pblk,
                                                     done, (float*)d_out);
}